// Round 3
// baseline (442.631 us; speedup 1.0000x reference)
//
#include <hip/hip_runtime.h>

// OU process sampling: solve upper-bidiagonal U x = z along last axis.
// x[i] = a[i]*x[i+1] + b[i],  a[i] = -sup[i+1]/diag[i] (a[L-1]=0), b[i] = z[i]/diag[i]
//
// One block per (B,C) row. Coalesced global<->LDS transpose (R1: the direct
// 64B-stride per-lane chunk pattern saturated the VMEM request pipe at ~2 TB/s,
// not HBM bytes). LDS padded +1 float per 32 -> conflict-free for both the
// coalesced staging order and the per-thread contiguous chunk order.
//
// R2 (431us, was 455): 16-barrier Hillis-Steele scan -> barrier-free in-wave
// __shfl_down suffix scan of affine maps + 8-entry cross-wave combine (3
// barriers, was 18); TPB 512, K=16.
//
// R4 (this version): solve ~98us vs 85.3us BW floor (dur_us includes ~330us
// of harness poison fills; top-5 all fillBuffer ~165us). The post-barrier
// critical path contained an L2 binv load (~200cy) feeding the bv multiply.
// bv = z*binv is elementwise in row position -> apply it on the STAGING side:
// load z4 and binv4 with the same coalesced index (binv L2-hot), multiply,
// stage the product. Post-barrier is now pure LDS/VALU. Also dropped the
// persistent bv[16] array (passes read products from LDS; slots are
// thread-exclusive, 2-way bank alias = free) -> -16 persistent VGPRs,
// protecting 4-blocks/CU residency (needs <=64 VGPR). Bitwise-same math.

#define LN  8192   // L
#define TPB 512    // threads per block
#define K   16     // LN / TPB, elements per thread
#define W   (TPB / 64)               // waves per block = 8
#define PADF(i) ((i) + ((i) >> 5))   // padded LDS float index
#define LDSF (LN + (LN >> 5))        // 8448 floats = 33 KB

__global__ void ou_prep(const float* __restrict__ diag,
                        const float* __restrict__ sup,
                        float* __restrict__ a,
                        float* __restrict__ binv) {
    int i = blockIdx.x * blockDim.x + threadIdx.x;
    if (i < LN) {
        float inv = 1.0f / diag[i];
        binv[i] = inv;
        float e = (i + 1 < LN) ? sup[i + 1] : 0.0f;  // e[L-1] = 0
        a[i] = -e * inv;
    }
}

__global__ __launch_bounds__(TPB) void ou_solve(
    const float* __restrict__ z,
    const float* __restrict__ a,
    const float* __restrict__ binv,
    float* __restrict__ out) {
    __shared__ float lds[LDSF];
    __shared__ float sAw[W];
    __shared__ float sBw[W];
    const int t = threadIdx.x;
    const int lane = t & 63;
    const int w = t >> 6;
    const long long rowbase = (long long)blockIdx.x * LN;

    // --- Stage b = z*binv into LDS, coalesced. binv4 uses the same index as
    //     z4 (row position), is 32KB L2-resident broadcast across all blocks.
    {
        const float4* z4 = reinterpret_cast<const float4*>(z + rowbase);
        const float4* bi4 = reinterpret_cast<const float4*>(binv);
#pragma unroll
        for (int m = 0; m < K / 4; ++m) {
            int gi = m * (TPB * 4) + 4 * t;
            float4 v = z4[m * TPB + t];
            float4 iv = bi4[m * TPB + t];
            v.x *= iv.x; v.y *= iv.y; v.z *= iv.z; v.w *= iv.w;
            int li = PADF(gi);  // 4t%32 + 3 <= 31: no pad boundary inside the 4
            lds[li + 0] = v.x; lds[li + 1] = v.y;
            lds[li + 2] = v.z; lds[li + 3] = v.w;
        }
    }

    // --- Per-thread chunk a-coefficients from global (L2-resident)
    float av[K];
    {
        const float4* a4 = reinterpret_cast<const float4*>(a + t * K);
#pragma unroll
        for (int j = 0; j < K / 4; ++j) {
            float4 aa = a4[j];
            av[4 * j + 0] = aa.x; av[4 * j + 1] = aa.y;
            av[4 * j + 2] = aa.z; av[4 * j + 3] = aa.w;
        }
    }
    __syncthreads();  // staging complete; post-barrier path is pure LDS/VALU

    // PADF(16t + j) = 16t + (t>>1) + j for j<16 (chunk never crosses a pad).
    // Scalar chunk reads: bank = (33u + 16s + j) mod 32, u=t>>1, s=t&1 ->
    // each bank hit exactly 2x per wave = free.
    const int lb = 16 * t + (t >> 1);

    // --- Pass 1: zero-boundary chunk solve -> affine map (Ax, Bx):
    //     x_head = Ax * x_entering + Bx.  b-values read from LDS.
    float Bx = 0.0f, Ax = 1.0f;
#pragma unroll
    for (int j = K - 1; j >= 0; --j) {
        Bx = fmaf(av[j], Bx, lds[lb + j]);
        Ax *= av[j];
    }

    // --- In-wave suffix scan of affine maps, barrier-free.
    //     Composition (A1,B1)∘(A2,B2) = (A1*A2, A1*B2 + B1), applied g2-first.
    //     After the loop lane i holds S_i = f_i ∘ ... ∘ f_63 (within wave).
#pragma unroll
    for (int off = 1; off < 64; off <<= 1) {
        float A2 = __shfl_down(Ax, off);
        float B2 = __shfl_down(Bx, off);
        if (lane + off < 64) {
            Bx = fmaf(Ax, B2, Bx);
            Ax *= A2;
        }
    }
    if (lane == 0) { sAw[w] = Ax; sBw[w] = Bx; }  // wave total T_w = S_0
    __syncthreads();

    // --- Cross-wave exclusive suffix: E_w = T_{w+1} ∘ ... ∘ T_{W-1}
    //     (uniform LDS broadcast reads, wave-uniform trip count)
    float Ae = 1.0f, Be = 0.0f;
    for (int ww = w + 1; ww < W; ++ww) {
        Be = fmaf(Ae, sBw[ww], Be);
        Ae *= sAw[ww];
    }

    // --- Entering x for this chunk = (S_{i+1} ∘ E_w)(0); for lane 63 the
    //     neighbor is the next wave's head: G_{t+1} = T_{w+1}∘E_{w+1} = E_w,
    //     i.e. identity ∘ E_w. Zero boundary falls out for the last thread.
    float As = __shfl_down(Ax, 1);
    float Bs = __shfl_down(Bx, 1);
    if (lane == 63) { As = 1.0f; Bs = 0.0f; }
    float xcur = fmaf(As, Be, Bs);

    // --- Pass 2: exact sweep; read b from LDS, overwrite slot with result
    //     (slots are thread-exclusive, read-then-write per element is safe)
#pragma unroll
    for (int j = K - 1; j >= 0; --j) {
        xcur = fmaf(av[j], xcur, lds[lb + j]);
        lds[lb + j] = xcur;
    }
    __syncthreads();

    // --- Coalesced store from LDS
    {
        float4* o4 = reinterpret_cast<float4*>(out + rowbase);
#pragma unroll
        for (int m = 0; m < K / 4; ++m) {
            int gi = m * (TPB * 4) + 4 * t;
            int li = PADF(gi);
            o4[m * TPB + t] = make_float4(lds[li + 0], lds[li + 1],
                                          lds[li + 2], lds[li + 3]);
        }
    }
}

extern "C" void kernel_launch(void* const* d_in, const int* in_sizes, int n_in,
                              void* d_out, int out_size, void* d_ws, size_t ws_size,
                              hipStream_t stream) {
    const float* z    = (const float*)d_in[0];   // (B, C, L) fp32
    const float* diag = (const float*)d_in[1];   // (L,)
    const float* sup  = (const float*)d_in[2];   // (L,)
    float* out = (float*)d_out;

    float* a    = (float*)d_ws;        // LN floats
    float* binv = a + LN;              // LN floats (64 KB total scratch)

    const int rows = in_sizes[0] / LN; // B*C = 8192

    ou_prep<<<(LN + TPB - 1) / TPB, TPB, 0, stream>>>(diag, sup, a, binv);
    ou_solve<<<rows, TPB, 0, stream>>>(z, a, binv, out);
}

// Round 5
// 429.963 us; speedup vs baseline: 1.0295x; 1.0295x over previous
//
#include <hip/hip_runtime.h>

// OU process sampling: solve upper-bidiagonal U x = z along last axis.
// x[i] = a[i]*x[i+1] + b[i],  a[i] = -sup[i+1]/diag[i] (a[L-1]=0), b[i] = z[i]/diag[i]
//
// One block per (B,C) row. Coalesced global<->LDS transpose (R1: the direct
// 64B-stride per-lane chunk pattern saturated the VMEM request pipe at ~2 TB/s,
// not HBM bytes). LDS padded +1 float per 32 -> conflict-free for both the
// coalesced staging order and the per-thread contiguous chunk order.
//
// R2 (431us, was 455): 16-barrier Hillis-Steele scan -> barrier-free in-wave
// __shfl_down suffix scan of affine maps + 8-entry cross-wave combine (3
// barriers, was 18); TPB 512, K=16.
//
// R4 (442us, REGRESSION -> reverted): binv multiply in staging doubled staging
// VMEM instructions; dropping bv[] doubled scalar LDS reads on serial passes.
//
// R5 (compile error): __builtin_nontemporal_* rejects HIP_vector_type<float,4>*.
// R6 (this version): same NT-hint plan via native clang ext_vector_type(4)
// floats (builtin-accepted, lowers to global_load/store_dwordx4 nt). z is
// read-once -> nt load; out write-once -> nt store; a/binv (64KB broadcast)
// stay temporal. Otherwise byte-identical to R2's 431us structure.

#define LN  8192   // L
#define TPB 512    // threads per block
#define K   16     // LN / TPB, elements per thread
#define W   (TPB / 64)               // waves per block = 8
#define PADF(i) ((i) + ((i) >> 5))   // padded LDS float index
#define LDSF (LN + (LN >> 5))        // 8448 floats = 33 KB

typedef float fx4 __attribute__((ext_vector_type(4)));

__global__ void ou_prep(const float* __restrict__ diag,
                        const float* __restrict__ sup,
                        float* __restrict__ a,
                        float* __restrict__ binv) {
    int i = blockIdx.x * blockDim.x + threadIdx.x;
    if (i < LN) {
        float inv = 1.0f / diag[i];
        binv[i] = inv;
        float e = (i + 1 < LN) ? sup[i + 1] : 0.0f;  // e[L-1] = 0
        a[i] = -e * inv;
    }
}

__global__ __launch_bounds__(TPB) void ou_solve(
    const float* __restrict__ z,
    const float* __restrict__ a,
    const float* __restrict__ binv,
    float* __restrict__ out) {
    __shared__ float lds[LDSF];
    __shared__ float sAw[W];
    __shared__ float sBw[W];
    const int t = threadIdx.x;
    const int lane = t & 63;
    const int w = t >> 6;
    const long long rowbase = (long long)blockIdx.x * LN;

    // --- Stage z into LDS, coalesced: thread t iter m covers floats 2048m+4t..+3
    //     z is touched exactly once kernel-wide -> non-temporal load.
    {
        const fx4* z4 = reinterpret_cast<const fx4*>(z + rowbase);
#pragma unroll
        for (int m = 0; m < K / 4; ++m) {
            int gi = m * (TPB * 4) + 4 * t;
            fx4 v = __builtin_nontemporal_load(&z4[m * TPB + t]);
            int li = PADF(gi);  // 4t%32 + 3 <= 31: no pad boundary inside the 4
            lds[li + 0] = v.x; lds[li + 1] = v.y;
            lds[li + 2] = v.z; lds[li + 3] = v.w;
        }
    }

    // --- Per-thread chunk coefficients from global (L2-resident, 64 KB total;
    //     broadcast to all blocks -> keep temporal)
    float av[K], bv[K];
    const int cb = t * K;
    {
        const float4* a4 = reinterpret_cast<const float4*>(a + cb);
#pragma unroll
        for (int j = 0; j < K / 4; ++j) {
            float4 aa = a4[j];
            av[4 * j + 0] = aa.x; av[4 * j + 1] = aa.y;
            av[4 * j + 2] = aa.z; av[4 * j + 3] = aa.w;
        }
    }
    __syncthreads();  // staging complete
    // PADF(16t + j) = 16t + (t>>1) + j for j<16 (chunk never crosses a pad)
    const int lb = 16 * t + (t >> 1);
    {
        const float4* i4 = reinterpret_cast<const float4*>(binv + cb);
#pragma unroll
        for (int j = 0; j < K / 4; ++j) {
            float4 ii = i4[j];  // fused load: no iv[K] array (VGPR pressure)
            bv[4 * j + 0] = lds[lb + 4 * j + 0] * ii.x;
            bv[4 * j + 1] = lds[lb + 4 * j + 1] * ii.y;
            bv[4 * j + 2] = lds[lb + 4 * j + 2] * ii.z;
            bv[4 * j + 3] = lds[lb + 4 * j + 3] * ii.w;
        }
    }

    // --- Pass 1: zero-boundary chunk solve -> affine map (Ax, Bx):
    //     x_head = Ax * x_entering + Bx
    float Bx = 0.0f, Ax = 1.0f;
#pragma unroll
    for (int j = K - 1; j >= 0; --j) {
        Bx = fmaf(av[j], Bx, bv[j]);
        Ax *= av[j];
    }

    // --- In-wave suffix scan of affine maps, barrier-free.
    //     Composition (A1,B1)∘(A2,B2) = (A1*A2, A1*B2 + B1), applied g2-first.
    //     After the loop lane i holds S_i = f_i ∘ ... ∘ f_63 (within wave).
#pragma unroll
    for (int off = 1; off < 64; off <<= 1) {
        float A2 = __shfl_down(Ax, off);
        float B2 = __shfl_down(Bx, off);
        if (lane + off < 64) {
            Bx = fmaf(Ax, B2, Bx);
            Ax *= A2;
        }
    }
    if (lane == 0) { sAw[w] = Ax; sBw[w] = Bx; }  // wave total T_w = S_0
    __syncthreads();

    // --- Cross-wave exclusive suffix: E_w = T_{w+1} ∘ ... ∘ T_{W-1}
    //     (uniform LDS broadcast reads, wave-uniform trip count)
    float Ae = 1.0f, Be = 0.0f;
    for (int ww = w + 1; ww < W; ++ww) {
        Be = fmaf(Ae, sBw[ww], Be);
        Ae *= sAw[ww];
    }

    // --- Entering x for this chunk = (S_{i+1} ∘ E_w)(0); for lane 63 the
    //     neighbor is the next wave's head: G_{t+1} = T_{w+1}∘E_{w+1} = E_w,
    //     i.e. identity ∘ E_w. Zero boundary falls out for the last thread.
    float As = __shfl_down(Ax, 1);
    float Bs = __shfl_down(Bx, 1);
    if (lane == 63) { As = 1.0f; Bs = 0.0f; }
    float xcur = fmaf(As, Be, Bs);

    // --- Pass 2: exact sweep; write results into own LDS chunk slots
    //     (slots are thread-exclusive; all reads of them happened pre-barrier)
#pragma unroll
    for (int j = K - 1; j >= 0; --j) {
        xcur = fmaf(av[j], xcur, bv[j]);
        lds[lb + j] = xcur;
    }
    __syncthreads();

    // --- Coalesced store from LDS; out never re-read -> non-temporal store
    {
        fx4* o4 = reinterpret_cast<fx4*>(out + rowbase);
#pragma unroll
        for (int m = 0; m < K / 4; ++m) {
            int gi = m * (TPB * 4) + 4 * t;
            int li = PADF(gi);
            fx4 v;
            v.x = lds[li + 0]; v.y = lds[li + 1];
            v.z = lds[li + 2]; v.w = lds[li + 3];
            __builtin_nontemporal_store(v, &o4[m * TPB + t]);
        }
    }
}

extern "C" void kernel_launch(void* const* d_in, const int* in_sizes, int n_in,
                              void* d_out, int out_size, void* d_ws, size_t ws_size,
                              hipStream_t stream) {
    const float* z    = (const float*)d_in[0];   // (B, C, L) fp32
    const float* diag = (const float*)d_in[1];   // (L,)
    const float* sup  = (const float*)d_in[2];   // (L,)
    float* out = (float*)d_out;

    float* a    = (float*)d_ws;        // LN floats
    float* binv = a + LN;              // LN floats (64 KB total scratch)

    const int rows = in_sizes[0] / LN; // B*C = 8192

    ou_prep<<<(LN + TPB - 1) / TPB, TPB, 0, stream>>>(diag, sup, a, binv);
    ou_solve<<<rows, TPB, 0, stream>>>(z, a, binv, out);
}